// Round 5
// baseline (582.881 us; speedup 1.0000x reference)
//
#include <hip/hip_runtime.h>
#include <float.h>
#include <math.h>

// Problem constants (fixed by the reference: N=8192, D=512, k+1=31).
#define NN 8192
#define DD 512
#define TOPK 31
#define CAPW 192          // per-wave candidate cap (typical cnt ~50)
#define DELTA 1e-4f       // sound |approx-exact| bound: lo*lo + requant ~5e-5

// Strategy (R12):
//   Bit-exact value chain (absmax 0.0 since R3):
//     h = relu(f*W1)*W2 ; n = sqrtf(numpy-pairwise sum h*h) ; e = h/n
//     sim[i][j] = sequential-k fmaf chain over e_i*e_j ; stable top-31
//   Approx sim = bf16 MFMA: e = hi+lo, acc = hi*hi + lo*hi + hi*lo.
//   NEW (R12): two-level candidate pruning.
//   - sim_mfma epilogue emits GM[row][512] = exact f32 max per 16-col group
//     (4 shfl_xor per value; replaces rmx/cmx/TM machinery entirely).
//   - topk_collect reads 2KB of GM per row instead of streaming the 128MB
//     scratch: tile max = max of 8 gmax (bit-identical to old TM -> same T),
//     groups with gmax < Tc provably contain no candidate -> only ~50 groups
//     (32B each) of scratch are touched. Same Tc, same candidate set.
//   - write_kernel zeroes the full 32KB row again (dedicated streamer).
//   Soundness: required j (exact top-31) has approx_j >= v31-2DELTA >= Tc;
//   its gmax >= approx_j (never skipped); stored RU >= approx_j (collected).

typedef __attribute__((ext_vector_type(8))) short short8;
typedef __attribute__((ext_vector_type(4))) float f32x4;

__device__ __forceinline__ float h_elem(const float* __restrict__ f,
                                        const float* __restrict__ W1,
                                        const float* __restrict__ W2, int k) {
  float x = f[k] * W1[k];
  x = fmaxf(x, 0.0f);
  return x * W2[k];
}

__device__ __forceinline__ unsigned short f2bf_rne(float x) {
  unsigned u = __float_as_uint(x);
  unsigned r = (u >> 16) & 1u;
  u += 0x7fffu + r;
  return (unsigned short)(u >> 16);
}
// Round toward +inf: guarantees bf16(x) >= x. (pos: ceil; neg: trunc->up)
__device__ __forceinline__ unsigned short f2bf_ru(float x) {
  unsigned u = __float_as_uint(x);
  if (!(u >> 31)) u += 0xffffu;
  return (unsigned short)(u >> 16);
}
__device__ __forceinline__ float bf2f(unsigned short h) {
  return __uint_as_float(((unsigned)h) << 16);
}
__device__ __forceinline__ unsigned ordmap(float x) {
  unsigned u = __float_as_uint(x);
  return (u & 0x80000000u) ? ~u : (u | 0x80000000u);
}

// async global->LDS, 16B per lane (dest = wave-uniform base + lane*16)
__device__ __forceinline__ void gl16(const void* g, void* l) {
  __builtin_amdgcn_global_load_lds(
      (const __attribute__((address_space(1))) void*)g,
      (__attribute__((address_space(3))) void*)l, 16, 0, 0);
}

// bf16 scratch image of sim row i: second half of output row i's 32KB span.
__device__ __forceinline__ unsigned short* bfrow(float* C, int row) {
  return (unsigned short*)C + (size_t)row * (2 * NN) + NN;
}

// ---------------------------------------------------------------------------
// Kernel A: fused norm (numpy pairwise association, bit-exact) + e = h/n,
// bf16 hi/lo split (RNE), flag zeroing. One wave per row.
// ---------------------------------------------------------------------------
__global__ __launch_bounds__(256) void emb_kernel(
    const float* __restrict__ f, const float* __restrict__ W1,
    const float* __restrict__ W2, float* __restrict__ e32,
    unsigned short* __restrict__ Ehi, unsigned short* __restrict__ Elo,
    int* __restrict__ flags) {
  const int lane = threadIdx.x & 63;
  const int row = blockIdx.x * 4 + (threadIdx.x >> 6);
  const float* fr = f + (size_t)row * DD;
  const int b = lane >> 4, L = lane & 15;
  if (lane == 0) flags[row] = 0;

  float s[8];
#pragma unroll
  for (int j = 0; j < 8; ++j) {
    float h = h_elem(fr, W1, W2, b * 128 + 16 * j + L);
    s[j] = h * h;
  }
  float v = ((s[0] + s[1]) + (s[2] + s[3])) + ((s[4] + s[5]) + (s[6] + s[7]));
  float t = v + __shfl_xor(v, 8);
  t = t + __shfl_xor(t, 4);
  t = t + __shfl_xor(t, 2);
  float nb = t + __shfl_xor(t, 1);
  float x = nb + __shfl_xor(nb, 16);
  float norm2 = x + __shfl_xor(x, 32);
  const float n = fmaxf(sqrtf(norm2), 1e-12f);

  float* er = e32 + (size_t)row * DD;
  unsigned short* hr = Ehi + (size_t)row * DD;
  unsigned short* lr = Elo + (size_t)row * DD;
#pragma unroll
  for (int m = 0; m < 8; ++m) {
    int k = m * 64 + lane;
    float e = h_elem(fr, W1, W2, k) / n;
    er[k] = e;
    unsigned short hb = f2bf_rne(e);
    hr[k] = hb;
    lr[k] = f2bf_rne(e - bf2f(hb));
  }
}

// ---------------------------------------------------------------------------
// Kernel B: merged 3-term bf16 MFMA sim, upper-triangle 128x128 tiles.
// 2-phase K-loop (BK=32): STAGE(next buf) -> frag reads + 48 MFMAs (cur buf)
// -> ONE __syncthreads. Linear LDS tiles AH|AL|BH|BL (8KB each) x 2 buffers.
// Epilogue: round-up bf16 tile write into per-row scratch halves + per-group
// f32 maxima GM (normal rows + mirror rows) + (bx>by) transposed mirror tile.
// ---------------------------------------------------------------------------
#define OFS_AL 4096   // short offsets into a buffer
#define OFS_BH 8192
#define OFS_BL 12288

#define STAGE(BUF, KK)                        \
  do {                                        \
    char* Ld = L0 + ((BUF) << 15);            \
    gl16(Ehi + rA + (KK), Ld);                \
    gl16(Ehi + rA + H + (KK), Ld + 4096);     \
    gl16(Elo + rA + (KK), Ld + 8192);         \
    gl16(Elo + rA + H + (KK), Ld + 12288);    \
    gl16(Ehi + rB + (KK), Ld + 16384);        \
    gl16(Ehi + rB + H + (KK), Ld + 20480);    \
    gl16(Elo + rB + (KK), Ld + 24576);        \
    gl16(Elo + rB + H + (KK), Ld + 28672);    \
  } while (0)

__global__ __launch_bounds__(256) void sim_mfma(
    const unsigned short* __restrict__ Ehi,
    const unsigned short* __restrict__ Elo, float* __restrict__ C,
    float* __restrict__ GM) {
  // triangular decode: 2080 blocks -> (bx, by) with bx >= by
  int rem = blockIdx.x, by = 0;
  while (rem >= 64 - by) { rem -= 64 - by; ++by; }
  const int bx = by + rem;

  __shared__ __align__(16) char smem[65536];  // 2 x 32KB ping-pong; epi alias
  unsigned short* S = (unsigned short*)smem;
  char* Sc = smem;
  float(*Tt)[133] = (float(*)[133])smem;  // epilogue alias ([64][133] = 34048B)

  const int t = threadIdx.x;
  const int lane = t & 63, w = t >> 6;
  const int wr = w >> 1, wc = w & 1;
  const int quad = lane >> 4, l16 = lane & 15;
  const int i0 = by * 128, j0 = bx * 128;

  f32x4 acc[4][4];
#pragma unroll
  for (int a = 0; a < 4; ++a)
#pragma unroll
    for (int b = 0; b < 4; ++b) acc[a][b] = (f32x4){0.f, 0.f, 0.f, 0.f};

  // staging: thread t writes LDS bytes [t*16, t*16+16) of each 4KB tensor-half
  // == row (t>>2), chunk (t&3) of a linear [128][32-short] tile.
  const size_t rA = (size_t)(i0 + (t >> 2)) * DD + (t & 3) * 8;
  const size_t rB = (size_t)(j0 + (t >> 2)) * DD + (t & 3) * 8;
  const size_t H = (size_t)64 * DD;
  char* L0 = Sc + (w << 10);  // wave-uniform LDS base

  STAGE(0, 0);
  __syncthreads();

  int cur = 0;
  for (int kk = 0; kk < DD; kk += 32) {
    if (kk + 32 < DD) STAGE(cur ^ 1, kk + 32);  // issue next tile's loads

    const unsigned short* Sb = S + (cur << 14);  // cur*16384 shorts
    short8 ah[4], al[4], bh[4];
#pragma unroll
    for (int mt = 0; mt < 4; ++mt) {
      int rr = (wr * 64 + mt * 16 + l16) * 32 + quad * 8;
      ah[mt] = *(const short8*)&Sb[rr];
      al[mt] = *(const short8*)&Sb[OFS_AL + rr];
    }
#pragma unroll
    for (int nt = 0; nt < 4; ++nt)
      bh[nt] = *(const short8*)&Sb[OFS_BH + (wc * 64 + nt * 16 + l16) * 32 + quad * 8];
#pragma unroll
    for (int mt = 0; mt < 4; ++mt)
#pragma unroll
      for (int nt = 0; nt < 4; ++nt)
        acc[mt][nt] = __builtin_amdgcn_mfma_f32_16x16x32_bf16(ah[mt], bh[nt], acc[mt][nt], 0, 0, 0);
#pragma unroll
    for (int mt = 0; mt < 4; ++mt)
#pragma unroll
      for (int nt = 0; nt < 4; ++nt)
        acc[mt][nt] = __builtin_amdgcn_mfma_f32_16x16x32_bf16(al[mt], bh[nt], acc[mt][nt], 0, 0, 0);
    short8 bl[4];
#pragma unroll
    for (int nt = 0; nt < 4; ++nt)
      bl[nt] = *(const short8*)&Sb[OFS_BL + (wc * 64 + nt * 16 + l16) * 32 + quad * 8];
#pragma unroll
    for (int mt = 0; mt < 4; ++mt)
#pragma unroll
      for (int nt = 0; nt < 4; ++nt)
        acc[mt][nt] = __builtin_amdgcn_mfma_f32_16x16x32_bf16(ah[mt], bl[nt], acc[mt][nt], 0, 0, 0);

    __syncthreads();  // drains next-buf loads + all waves done reading cur
    cur ^= 1;
  }

  // --- normal tile write: round-up bf16 into per-row scratch ---
#pragma unroll
  for (int mt = 0; mt < 4; ++mt)
#pragma unroll
    for (int r = 0; r < 4; ++r) {
      int row = i0 + wr * 64 + mt * 16 + quad * 4 + r;
      unsigned short* Br = bfrow(C, row) + j0 + wc * 64;
#pragma unroll
      for (int nt = 0; nt < 4; ++nt) Br[nt * 16 + l16] = f2bf_ru(acc[mt][nt][r]);
    }

  // --- per-row 16-col group maxima (exact f32), normal rows ---
  // row = i0+wr*64+mt*16+quad*4+r ; group = j0/16 + wc*4 + nt
#pragma unroll
  for (int mt = 0; mt < 4; ++mt)
#pragma unroll
    for (int nt = 0; nt < 4; ++nt)
#pragma unroll
      for (int r = 0; r < 4; ++r) {
        float m = acc[mt][nt][r];
        m = fmaxf(m, __shfl_xor(m, 1));
        m = fmaxf(m, __shfl_xor(m, 2));
        m = fmaxf(m, __shfl_xor(m, 4));
        m = fmaxf(m, __shfl_xor(m, 8));
        if (l16 == 0)
          GM[(size_t)(i0 + wr * 64 + mt * 16 + quad * 4 + r) * 512 +
             (j0 >> 4) + wc * 4 + nt] = m;
      }

  if (bx > by) {
    // --- mirror rows' group maxima: row = j0+wc*64+nt*16+l16,
    //     group = i0/16 + wr*4 + mt (max over r regs + quad lanes) ---
#pragma unroll
    for (int nt = 0; nt < 4; ++nt)
#pragma unroll
      for (int mt = 0; mt < 4; ++mt) {
        float c = fmaxf(fmaxf(acc[mt][nt][0], acc[mt][nt][1]),
                        fmaxf(acc[mt][nt][2], acc[mt][nt][3]));
        c = fmaxf(c, __shfl_xor(c, 16));
        c = fmaxf(c, __shfl_xor(c, 32));
        if (quad == 0)
          GM[(size_t)(j0 + wc * 64 + nt * 16 + l16) * 512 +
             (i0 >> 4) + wr * 4 + mt] = c;
      }

    // --- transposed mirror write via LDS strips (Tt aliases S), bf16-RU out ---
    for (int s = 0; s < 2; ++s) {
      __syncthreads();
      if (wc == s) {
#pragma unroll
        for (int mt = 0; mt < 4; ++mt)
#pragma unroll
          for (int nt = 0; nt < 4; ++nt)
#pragma unroll
            for (int r = 0; r < 4; ++r)
              Tt[nt * 16 + l16][wr * 64 + mt * 16 + quad * 4 + r] = acc[mt][nt][r];
      }
      __syncthreads();
#pragma unroll
      for (int q = 0; q < 8; ++q) {
        int fi = q * 256 + t;
        int rr = fi >> 5;
        int cc4 = (fi & 31) * 4;
        ushort4 v;
        v.x = f2bf_ru(Tt[rr][cc4]);
        v.y = f2bf_ru(Tt[rr][cc4 + 1]);
        v.z = f2bf_ru(Tt[rr][cc4 + 2]);
        v.w = f2bf_ru(Tt[rr][cc4 + 3]);
        *(ushort4*)(bfrow(C, j0 + s * 64 + rr) + i0 + cc4) = v;
      }
    }
  }
}

// ---------------------------------------------------------------------------
// Kernel C1: collect. One WAVE per row. Lane l owns groups 8l..8l+7 (2KB GM
// read, coalesced); tile max = max of its 8 gmax (bit-identical to old TM);
// T = 31st tile max via rank-select; only groups with gmax >= Tc are scanned
// (32B of scratch each). Exact fmaf chains re-rank; emit KV[row][31].
// Overflow -> flag (cleanup rewrites the row).
// ---------------------------------------------------------------------------
__global__ __launch_bounds__(256) void topk_collect(
    const float* __restrict__ C, const float* __restrict__ e32,
    const float* __restrict__ GM, int* __restrict__ flags,
    int2* __restrict__ KV) {
  const int w = threadIdx.x >> 6;
  const int lane = threadIdx.x & 63;
  const int row = blockIdx.x * 4 + w;

  __shared__ float er[4][DD];
  __shared__ int cidx[4][CAPW];
  __shared__ float cval[4][CAPW];
  __shared__ int wcnt[4];

  {
    const float4* e4 = (const float4*)(e32 + (size_t)row * DD);
    float4* er4 = (float4*)er[w];
    er4[lane] = e4[lane];
    er4[64 + lane] = e4[64 + lane];
  }
  if (lane == 0) wcnt[w] = 0;

  // GM row: lane l reads groups 8l..8l+7
  const float4* gm4 = (const float4*)(GM + (size_t)row * 512);
  float4 ga = gm4[lane * 2];
  float4 gb = gm4[lane * 2 + 1];
  float gv[8] = {ga.x, ga.y, ga.z, ga.w, gb.x, gb.y, gb.z, gb.w};

  // tile max (tile = lane) = max of its 8 group maxima (exact)
  float mv = fmaxf(fmaxf(fmaxf(gv[0], gv[1]), fmaxf(gv[2], gv[3])),
                   fmaxf(fmaxf(gv[4], gv[5]), fmaxf(gv[6], gv[7])));

  // T = 31st largest of 64 tile maxima: rank-select, independent shuffles.
  unsigned key = ordmap(mv);
  int rank = 0;
#pragma unroll
  for (int off = 1; off < 64; ++off) {
    int ol = (lane + off) & 63;
    unsigned ok = __shfl(key, ol);
    rank += (ok > key || (ok == key && ol < lane)) ? 1 : 0;
  }
  unsigned long long bmsk = __ballot(rank == TOPK - 1);
  float T = __shfl(mv, __ffsll((unsigned long long)bmsk) - 1);

  // scan only passing groups (gmax >= Tc -> may contain a candidate)
  const float Tc = T - 2.0f * DELTA;
  const unsigned short* Brow =
      (const unsigned short*)C + (size_t)row * (2 * NN) + NN;
#pragma unroll
  for (int q = 0; q < 8; ++q) {
    if (gv[q] >= Tc) {
      int col0 = (lane * 8 + q) * 16;
      const uint4* p4 = (const uint4*)(Brow + col0);
      uint4 a = p4[0], b = p4[1];
      unsigned arr[8] = {a.x, a.y, a.z, a.w, b.x, b.y, b.z, b.w};
#pragma unroll
      for (int c = 0; c < 8; ++c) {
        float f0 = __uint_as_float(arr[c] << 16);
        float f1 = __uint_as_float(arr[c] & 0xffff0000u);
        if (f0 >= Tc) { int p = atomicAdd(&wcnt[w], 1); if (p < CAPW) cidx[w][p] = col0 + 2 * c; }
        if (f1 >= Tc) { int p = atomicAdd(&wcnt[w], 1); if (p < CAPW) cidx[w][p] = col0 + 2 * c + 1; }
      }
    }
  }
  const int cnt = wcnt[w];

  if (cnt > CAPW) {
    if (lane == 0) flags[row] = 1;
    return;
  }

  // exact sequential-k fmaf chains (bit-identical to the verified chain)
  for (int c = lane; c < cnt; c += 64) {
    const float4* ej4 = (const float4*)(e32 + (size_t)cidx[w][c] * DD);
    float a = 0.f;
    for (int k4 = 0; k4 < DD / 4; ++k4) {
      float4 vv = ej4[k4];
      const float* e = &er[w][k4 * 4];
      a = fmaf(e[0], vv.x, a);
      a = fmaf(e[1], vv.y, a);
      a = fmaf(e[2], vv.z, a);
      a = fmaf(e[3], vv.w, a);
    }
    cval[w][c] = a;
  }

  // stable top-31 by (exact desc, idx asc) -> KV pairs
  for (int c = lane; c < cnt; c += 64) {
    float v = cval[w][c];
    int idx = cidx[w][c];
    int rnk = 0;
    for (int c2 = 0; c2 < cnt; ++c2) {
      float v2 = cval[w][c2];
      if (v2 > v || (v2 == v && cidx[w][c2] < idx)) ++rnk;
    }
    if (rnk < TOPK)
      KV[(size_t)row * TOPK + rnk] =
          make_int2(idx, __float_as_int(fmaxf(v, 0.0f)));
  }
}

// ---------------------------------------------------------------------------
// Kernel C2: writer. One block per row: streaming float4 zero-fill of the
// full 32KB row (also overwrites the bf16 scratch half), barrier (drains
// stores), then lanes 0..30 scatter the 31 values. Pure write-BW bound.
// ---------------------------------------------------------------------------
__global__ __launch_bounds__(256) void write_kernel(float* __restrict__ C,
                                                    const int2* __restrict__ KV) {
  const int row = blockIdx.x;
  const int t = threadIdx.x;
  int j = 0;
  float v = 0.f;
  if (t < TOPK) {
    int2 p = KV[(size_t)row * TOPK + t];
    j = p.x & (NN - 1);
    v = __int_as_float(p.y);
  }
  const float4 z = make_float4(0.f, 0.f, 0.f, 0.f);
  float4* Cw4 = (float4*)(C + (size_t)row * NN);
#pragma unroll
  for (int i = 0; i < NN / 4 / 256; ++i) Cw4[i * 256 + t] = z;
  __syncthreads();  // vmcnt(0) drain: zeros committed before value stores
  if (t < TOPK) C[(size_t)row * NN + j] = v;
}

// ---------------------------------------------------------------------------
// Kernel D: exact cleanup for flagged rows (statistically never executes).
// ---------------------------------------------------------------------------
__global__ __launch_bounds__(256) void cleanup_kernel(
    float* __restrict__ C, const float* __restrict__ e32,
    const int* __restrict__ flags) {
  const int row = blockIdx.x;
  if (flags[row] == 0) return;
  const int tid = threadIdx.x;
  const int lane = tid & 63, wid = tid >> 6;

  __shared__ float sv[NN];
  __shared__ float er[DD];
  __shared__ unsigned long long wred[4];
  __shared__ int kidx[TOPK];
  __shared__ float kval[TOPK];

  {
    const float4* e4 = (const float4*)(e32 + (size_t)row * DD);
    if (tid < DD / 4) ((float4*)er)[tid] = e4[tid];
  }
  __syncthreads();

  for (int m = 0; m < NN / 256; ++m) {
    int j = m * 256 + tid;
    const float* ej = e32 + (size_t)j * DD;
    float a = 0.f;
    for (int k = 0; k < DD; k += 4) {
      float4 v = *(const float4*)&ej[k];
      a = fmaf(er[k], v.x, a);
      a = fmaf(er[k + 1], v.y, a);
      a = fmaf(er[k + 2], v.z, a);
      a = fmaf(er[k + 3], v.w, a);
    }
    sv[j] = a;
  }
  __syncthreads();

  for (int it = 0; it < TOPK; ++it) {
    float bv = -FLT_MAX;
    int bi = 0;
    for (int j = tid; j < NN; j += 256) {
      float v = sv[j];
      if (v > bv) { bv = v; bi = j; }
    }
    unsigned long long key =
        ((unsigned long long)ordmap(bv) << 32) | (unsigned)(NN - 1 - bi);
#pragma unroll
    for (int off = 32; off; off >>= 1) {
      unsigned long long o = __shfl_xor(key, off);
      if (o > key) key = o;
    }
    if (lane == 0) wred[wid] = key;
    __syncthreads();
    if (tid == 0) {
      unsigned long long k0 = wred[0];
      if (wred[1] > k0) k0 = wred[1];
      if (wred[2] > k0) k0 = wred[2];
      if (wred[3] > k0) k0 = wred[3];
      int idx = (NN - 1) - (int)(k0 & 0xFFFFFFFFu);
      kidx[it] = idx;
      kval[it] = sv[idx];
      sv[idx] = -FLT_MAX;
    }
    __syncthreads();
  }

  float4 z4 = make_float4(0.f, 0.f, 0.f, 0.f);
  float4* sv4 = (float4*)sv;
  for (int i = tid; i < NN / 4; i += 256) sv4[i] = z4;
  __syncthreads();
  if (tid < TOPK) sv[kidx[tid]] = fmaxf(kval[tid], 0.0f);
  __syncthreads();
  float4* Cw4 = (float4*)(C + (size_t)row * NN);
  for (int i = tid; i < NN / 4; i += 256) Cw4[i] = sv4[i];
}

// ---------------------------------------------------------------------------
extern "C" void kernel_launch(void* const* d_in, const int* in_sizes, int n_in,
                              void* d_out, int out_size, void* d_ws,
                              size_t ws_size, hipStream_t stream) {
  const float* f = (const float*)d_in[0];
  const float* W1 = (const float*)d_in[1];
  const float* W2 = (const float*)d_in[2];
  float* out = (float*)d_out;
  char* ws = (char*)d_ws;
  float* e32 = (float*)ws;                                     // 16 MiB
  unsigned short* Ehi = (unsigned short*)(ws + (size_t)NN * DD * 4);   // 8 MiB
  unsigned short* Elo = (unsigned short*)(ws + (size_t)NN * DD * 6);   // 8 MiB
  float* GM = (float*)(ws + (size_t)NN * DD * 8);              // 16 MiB (NN*512)
  int* flags = (int*)(ws + (size_t)NN * DD * 8 + (size_t)NN * 512 * 4);  // 32 KB
  int2* KV = (int2*)(ws + (size_t)NN * DD * 8 + (size_t)NN * 512 * 4 +
                     (size_t)NN * 4);  // ~2 MiB (8192*31*8 B)

  emb_kernel<<<NN / 4, 256, 0, stream>>>(f, W1, W2, e32, Ehi, Elo, flags);
  sim_mfma<<<2080, 256, 0, stream>>>(Ehi, Elo, out, GM);
  topk_collect<<<NN / 4, 256, 0, stream>>>(out, e32, GM, flags, KV);
  write_kernel<<<NN, 256, 0, stream>>>(out, KV);
  cleanup_kernel<<<NN, 256, 0, stream>>>(out, e32, flags);
}